// Round 7
// baseline (129.796 us; speedup 1.0000x reference)
//
#include <hip/hip_runtime.h>

#define NS 1024
#define KD 256
#define H  256
#define PAIR_NBLK 512

#define GLOAD_LDS16(gp, lp)                                                         \
    __builtin_amdgcn_global_load_lds(                                               \
        (const __attribute__((address_space(1))) void*)(gp),                        \
        (__attribute__((address_space(3))) void*)(lp), 16, 0, 0)

// ---------------------------------------------------------------------------
// proj: PXW[h'][j] = |w2_h| * (x_j . W1[:,h])            (h' = sign-partition perm)
//       PYW[h'][i] = |w2_h| * (y_i . W1[KD+,h] + b1[h])
//       FX[j] = sum_h w2_h * px[h][j],  GY[i] = sum_h w2_h * (py[h][i]+b1[h])
// grid (8, 32, 2), block 256.
// ---------------------------------------------------------------------------
__global__ __launch_bounds__(256) void proj_kernel(
    const float* __restrict__ X, const float* __restrict__ Y,
    const float* __restrict__ W1, const float* __restrict__ b1,
    const float* __restrict__ W2,
    float* __restrict__ PXW, float* __restrict__ PYW,
    float* __restrict__ FX, float* __restrict__ GY)
{
    __shared__ float xs[KD][34];    // transposed [k][sample-local]
    __shared__ float fred[8][33];
    __shared__ int dsts[H];
    __shared__ int woff[4];

    const int tid = threadIdx.x;

    // sign-partition permutation of h (w2>=0 first, stable) -- validated in R4
    {
        const float w = W2[tid];
        const bool pos = (w >= 0.0f);
        const unsigned long long m = __ballot(pos);
        const int lane = tid & 63, wv = tid >> 6;
        const int below = __popcll(m & ((1ull << lane) - 1ull));
        if (lane == 0) woff[wv] = __popcll(m);
        __syncthreads();
        const int npos = woff[0] + woff[1] + woff[2] + woff[3];
        int posbase = 0;
        #pragma unroll
        for (int q = 0; q < 4; ++q) if (q < wv) posbase += woff[q];
        const int negbase = npos + (wv * 64 - posbase);
        dsts[tid] = pos ? (posbase + below) : (negbase + ((tid & 63) - below));
    }

    const int z = blockIdx.z;
    const float* __restrict__ A = z ? Y : X;
    const float* __restrict__ W = W1 + (z ? (size_t)KD * H : 0);
    float* __restrict__ OUT = z ? PYW : PXW;
    float* __restrict__ RS  = z ? GY : FX;

    const int jl = tid & 31;        // sample within block
    const int hg = tid >> 5;        // 0..7, 4 h's each
    const int i0 = blockIdx.y * 32, h0 = blockIdx.x * 32;

    // stage A rows transposed (32 rows x 256 k), once
    {
        const int ii = tid & 31, q = tid >> 5;
        #pragma unroll
        for (int u = 0; u < 8; ++u) {
            const int k = u * 32 + q * 4;
            float4 v = *(const float4*)&A[(i0 + ii) * KD + k];
            xs[k + 0][ii] = v.x; xs[k + 1][ii] = v.y;
            xs[k + 2][ii] = v.z; xs[k + 3][ii] = v.w;
        }
    }
    __syncthreads();   // publishes xs AND dsts

    float acc[4] = {};
    const float* __restrict__ wp = &W[h0 + hg * 4];
    #pragma unroll 8
    for (int k = 0; k < KD; ++k) {
        float4 w4 = *(const float4*)&wp[(size_t)k * H];
        const float xv = xs[k][jl];
        acc[0] = fmaf(xv, w4.x, acc[0]);
        acc[1] = fmaf(xv, w4.y, acc[1]);
        acc[2] = fmaf(xv, w4.z, acc[2]);
        acc[3] = fmaf(xv, w4.w, acc[3]);
    }

    if (z) {
        float4 bv = *(const float4*)&b1[h0 + hg * 4];
        acc[0] += bv.x; acc[1] += bv.y; acc[2] += bv.z; acc[3] += bv.w;
    }

    float4 w2v = *(const float4*)&W2[h0 + hg * 4];
    const float w2a[4] = {w2v.x, w2v.y, w2v.z, w2v.w};
    int d4[4];
    *(int4*)d4 = *(const int4*)&dsts[h0 + hg * 4];

    float fp = 0.f;
    #pragma unroll
    for (int c = 0; c < 4; ++c) {
        OUT[(size_t)d4[c] * NS + i0 + jl] = acc[c] * fabsf(w2a[c]);  // coalesced in j
        fp = fmaf(w2a[c], acc[c], fp);
    }
    fred[hg][jl] = fp;
    __syncthreads();
    if (tid < 32) {
        float s = 0.f;
        #pragma unroll
        for (int g = 0; g < 8; ++g) s += fred[g][tid];
        atomicAdd(&RS[i0 + tid], s);
    }
}

// ---------------------------------------------------------------------------
// pair: tile 128 j x 16 i, grid (8,64)=512 blocks. 16-h chunks, 4 LDS buffers,
// 3 tiles in flight via global_load_lds; counted s_waitcnt vmcnt(N) + raw
// s_barrier per chunk (loads stay in flight across barriers).
// inner per hh: px b64 (per-lane) + py b128 (uniform broadcast);
// accP/accN += |pyw + pxw| (sign handled by the h-permutation + Npos split).
// t1 = 0.5*(accP-accN + FX_j + GY_i) + b2 - 1. exp-sum + diag; last block
// finalizes out.
// ---------------------------------------------------------------------------
__global__ __launch_bounds__(256, 2) void pair_kernel(
    const float* __restrict__ PXW, const float* __restrict__ PYW,
    const float* __restrict__ W2, const float* __restrict__ b2,
    const float* __restrict__ FX, const float* __restrict__ GY,
    float* __restrict__ eparts, float* __restrict__ dparts,
    int* __restrict__ counter, float* __restrict__ out)
{
    __shared__ float pxs[4][16][128];   // 32 KB, 4-deep ring
    __shared__ float pys[256][16];      // 16 KB
    __shared__ float red_e[256], red_d[256];
    __shared__ double sde[256], sdd[256];
    __shared__ int wcnt[4];
    __shared__ int lastflag;

    const int tid = threadIdx.x;
    const int lane = tid & 63;
    const int wid = __builtin_amdgcn_readfirstlane(tid >> 6);
    const int j0 = blockIdx.x * 128;
    const int i0 = blockIdx.y * 16;

    // Npos (same ballot as proj -> same value)
    {
        const float w = W2[tid];
        const unsigned long long m = __ballot(w >= 0.0f);
        if (lane == 0) wcnt[wid] = __popcll(m);
    }
    __syncthreads();
    const int Npos = __builtin_amdgcn_readfirstlane(wcnt[0] + wcnt[1] + wcnt[2] + wcnt[3]);

    // stage pys via global_load_lds (linear dest, conflict-free): 4 insts/wave
    {
        float* pysf = &pys[0][0];
        #pragma unroll
        for (int q = 0; q < 4; ++q) {
            const int seg = wid * 4 + q;               // 0..15, 16 h-rows each
            const int h = seg * 16 + (lane >> 2);
            const float* g = &PYW[(size_t)h * NS + i0 + (lane & 3) * 4];
            GLOAD_LDS16(g, pysf + seg * 256 + lane * 4);
        }
    }

#define STAGE(T)                                                                \
    {                                                                           \
        const int _b = (T) & 3;                                                 \
        _Pragma("unroll")                                                       \
        for (int p = 0; p < 2; ++p) {                                           \
            const int hrow = p * 8 + wid * 2 + (lane >> 5);                     \
            const float* g = &PXW[(size_t)((T) * 16 + hrow) * NS + j0 + (lane & 31) * 4]; \
            GLOAD_LDS16(g, &pxs[_b][hrow][(lane & 31) * 4]);                    \
        }                                                                       \
    }

    STAGE(0); STAGE(1); STAGE(2);   // 3 tiles in flight (6 loads) + 4 py loads

    float accP[4][2] = {}, accN[4][2] = {};

#define CELLS(ACC)                                                              \
    _Pragma("unroll")                                                           \
    for (int hh = 0; hh < 16; ++hh) {                                           \
        float2 px2 = *(const float2*)(pxb + hh * 128);                          \
        float4 p4  = *(const float4*)(pyb + hh * 16);                           \
        const float pya[4] = {p4.x, p4.y, p4.z, p4.w};                          \
        _Pragma("unroll")                                                       \
        for (int r = 0; r < 4; ++r) {                                           \
            ACC[r][0] += fabsf(pya[r] + px2.x);                                 \
            ACC[r][1] += fabsf(pya[r] + px2.y);                                 \
        }                                                                       \
    }

    for (int T = 0; T < 16; ++T) {
        // counted wait: oldest in-flight tile (and pys on T=0) completed
        if (T <= 13)      asm volatile("s_waitcnt vmcnt(4)" ::: "memory");
        else if (T == 14) asm volatile("s_waitcnt vmcnt(2)" ::: "memory");
        else              asm volatile("s_waitcnt vmcnt(0)" ::: "memory");
        __builtin_amdgcn_sched_barrier(0);
        __builtin_amdgcn_s_barrier();
        __builtin_amdgcn_sched_barrier(0);

        if (T < 13) STAGE(T + 3);   // refill ring (buffer freed by the barrier)

        const int hbase = T * 16;
        const float* pxb = &pxs[T & 3][0][lane * 2];
        const float* pyb = &pys[hbase][wid * 4];

        if (hbase + 16 <= Npos) {
            CELLS(accP)
        } else if (hbase >= Npos) {
            CELLS(accN)
        } else {
            #pragma unroll
            for (int hh = 0; hh < 16; ++hh) {
                float2 px2 = *(const float2*)(pxb + hh * 128);
                float4 p4  = *(const float4*)(pyb + hh * 16);
                const float pya[4] = {p4.x, p4.y, p4.z, p4.w};
                if (hbase + hh < Npos) {
                    #pragma unroll
                    for (int r = 0; r < 4; ++r) {
                        accP[r][0] += fabsf(pya[r] + px2.x);
                        accP[r][1] += fabsf(pya[r] + px2.y);
                    }
                } else {
                    #pragma unroll
                    for (int r = 0; r < 4; ++r) {
                        accN[r][0] += fabsf(pya[r] + px2.x);
                        accN[r][1] += fabsf(pya[r] + px2.y);
                    }
                }
            }
        }
    }

    // epilogue: t1 = 0.5*(A + G_i + F_j) + (b2-1)
    const float c0 = b2[0] - 1.0f;
    float2 fx2 = *(const float2*)&FX[j0 + lane * 2];
    float4 g4 = *(const float4*)&GY[i0 + wid * 4];
    const float gya[4] = {g4.x, g4.y, g4.z, g4.w};
    const float fxa[2] = {fx2.x, fx2.y};

    float esum = 0.f, dsum = 0.f;
    #pragma unroll
    for (int r = 0; r < 4; ++r) {
        const int irow = i0 + wid * 4 + r;
        #pragma unroll
        for (int c = 0; c < 2; ++c) {
            const float A = accP[r][c] - accN[r][c];
            const float t1 = fmaf(0.5f, A + gya[r] + fxa[c], c0);
            esum += expf(t1);
            if (irow == j0 + lane * 2 + c) dsum += t1 + 1.0f;
        }
    }

    red_e[tid] = esum;
    red_d[tid] = dsum;
    __syncthreads();
    for (int s = 128; s > 0; s >>= 1) {
        if (tid < s) {
            red_e[tid] += red_e[tid + s];
            red_d[tid] += red_d[tid + s];
        }
        __syncthreads();
    }

    const int bid = blockIdx.y * gridDim.x + blockIdx.x;   // 0..511
    if (tid == 0) {
        __hip_atomic_store(&eparts[bid], red_e[0], __ATOMIC_RELAXED, __HIP_MEMORY_SCOPE_AGENT);
        __hip_atomic_store(&dparts[bid], red_d[0], __ATOMIC_RELAXED, __HIP_MEMORY_SCOPE_AGENT);
        __threadfence();
        const int prev = __hip_atomic_fetch_add(counter, 1, __ATOMIC_ACQ_REL, __HIP_MEMORY_SCOPE_AGENT);
        lastflag = (prev == PAIR_NBLK - 1);
    }
    __syncthreads();

    if (lastflag) {
        __threadfence();
        sde[tid] = (double)__hip_atomic_load(&eparts[tid], __ATOMIC_RELAXED, __HIP_MEMORY_SCOPE_AGENT)
                 + (double)__hip_atomic_load(&eparts[tid + 256], __ATOMIC_RELAXED, __HIP_MEMORY_SCOPE_AGENT);
        sdd[tid] = (double)__hip_atomic_load(&dparts[tid], __ATOMIC_RELAXED, __HIP_MEMORY_SCOPE_AGENT)
                 + (double)__hip_atomic_load(&dparts[tid + 256], __ATOMIC_RELAXED, __HIP_MEMORY_SCOPE_AGENT);
        __syncthreads();
        for (int s = 128; s > 0; s >>= 1) {
            if (tid < s) { sde[tid] += sde[tid + s]; sdd[tid] += sdd[tid + s]; }
            __syncthreads();
        }
        if (tid == 0)
            out[0] = (float)(sdd[0] / (double)NS - sde[0] / ((double)NS * (double)NS));
    }
#undef STAGE
#undef CELLS
}

// ---------------------------------------------------------------------------
extern "C" void kernel_launch(void* const* d_in, const int* in_sizes, int n_in,
                              void* d_out, int out_size, void* d_ws, size_t ws_size,
                              hipStream_t stream)
{
    const float* X  = (const float*)d_in[0];
    const float* Y  = (const float*)d_in[1];
    const float* W1 = (const float*)d_in[2];
    const float* b1 = (const float*)d_in[3];
    const float* W2 = (const float*)d_in[4];
    const float* b2 = (const float*)d_in[5];
    float* out = (float*)d_out;

    float* PXW    = (float*)d_ws;            // [H][NS] permuted, |w|-scaled
    float* PYW    = PXW + (size_t)H * NS;    // [H][NS]
    float* eparts = PYW + (size_t)H * NS;    // [512]
    float* dparts = eparts + 512;            // [512]
    float* FX     = dparts + 512;            // [1024]
    float* GY     = FX + NS;                 // [1024]
    int*   counter = (int*)(GY + NS);        // [1]

    // zero FX, GY, counter (contiguous)
    hipMemsetAsync(FX, 0, (size_t)(2 * NS) * sizeof(float) + sizeof(int), stream);

    proj_kernel<<<dim3(8, 32, 2), 256, 0, stream>>>(X, Y, W1, b1, W2, PXW, PYW, FX, GY);
    pair_kernel<<<dim3(8, 64), 256, 0, stream>>>(PXW, PYW, W2, b2, FX, GY,
                                                 eparts, dparts, counter, out);
}